// Round 6
// baseline (567.743 us; speedup 1.0000x reference)
//
#include <hip/hip_runtime.h>
#include <hip/hip_bf16.h>
#include <stdint.h>

#define SEQ    2048
#define HDIM   64
#define NHEAD  16
#define NBATCH 2
#define HID    1024
#define MAXP   2048
#define LOG2E  1.44269504f

typedef __attribute__((ext_vector_type(8))) short bf16x8;
typedef __attribute__((ext_vector_type(4))) float f32x4;

#define MFMA16(a,b,c) __builtin_amdgcn_mfma_f32_16x16x32_bf16((a),(b),(c),0,0,0)

static __device__ __forceinline__ unsigned short f2bf(float x){
  union { __hip_bfloat16 h; unsigned short u; } c; c.h = __float2bfloat16(x); return c.u;
}
static __device__ __forceinline__ float bf2f(unsigned short u){
  union { __hip_bfloat16 h; unsigned short u; } c; c.u = u; return __bfloat162float(c.h);
}
static __device__ __forceinline__ unsigned cvtpk(float lo, float hi){
  unsigned r;
  asm volatile("v_cvt_pk_bf16_f32 %0, %1, %2" : "=v"(r) : "v"(lo), "v"(hi));
  return r;
}

// ---------------- f32 -> bf16 convert ----------------
__global__ void cvt_kernel(const float* __restrict__ src, unsigned short* __restrict__ dst, int n4){
  int i = blockIdx.x*blockDim.x + threadIdx.x;
  int stride = gridDim.x*blockDim.x;
  for (int idx = i; idx < n4; idx += stride){
    float4 v = reinterpret_cast<const float4*>(src)[idx];
    ushort4 o;
    o.x = f2bf(v.x); o.y = f2bf(v.y); o.z = f2bf(v.z); o.w = f2bf(v.w);
    reinterpret_cast<ushort4*>(dst)[idx] = o;
  }
}

// ---------------- QKV projection GEMM ----------------
__global__ __launch_bounds__(256,2) void qkv_gemm(
    const unsigned short* __restrict__ X,
    const unsigned short* __restrict__ Wq_, const unsigned short* __restrict__ Wk_,
    const unsigned short* __restrict__ Wv_,
    const float* __restrict__ bq_, const float* __restrict__ bk_, const float* __restrict__ bv_,
    unsigned short* __restrict__ Qb, unsigned short* __restrict__ Kb, unsigned short* __restrict__ Vb)
{
  __shared__ __align__(16) unsigned short Al[128*72];
  __shared__ __align__(16) unsigned short Bl[128*72];
  const int tid = threadIdx.x;
  const int ln = tid & 63, wv = tid >> 6;
  const int l15 = ln & 15, g = ln >> 4;
  const int wr = wv >> 1, wc = wv & 1;

  const int bn = blockIdx.x, bm = blockIdx.y, mat = blockIdx.z;
  const unsigned short* W = (mat==0) ? Wq_ : ((mat==1) ? Wk_ : Wv_);
  const float* bias = (mat==0) ? bq_ : ((mat==1) ? bk_ : bv_);
  unsigned short* Out = (mat==0) ? Qb : ((mat==1) ? Kb : Vb);

  const int m0 = bm*128, n0 = bn*128;

  f32x4 acc[4][4];
  #pragma unroll
  for (int i=0;i<4;++i)
    #pragma unroll
    for (int j=0;j<4;++j) acc[i][j] = (f32x4){0.f,0.f,0.f,0.f};

  for (int kk = 0; kk < HID; kk += 64){
    #pragma unroll
    for (int p=0;p<4;++p){
      int lin = tid + 256*p;
      int row = lin >> 3, ch = lin & 7;
      *reinterpret_cast<bf16x8*>(&Al[row*72 + ch*8]) =
        *reinterpret_cast<const bf16x8*>(&X[(size_t)(m0+row)*HID + kk + ch*8]);
      *reinterpret_cast<bf16x8*>(&Bl[row*72 + ch*8]) =
        *reinterpret_cast<const bf16x8*>(&W[(size_t)(n0+row)*HID + kk + ch*8]);
    }
    __syncthreads();
    bf16x8 a0[4], a1[4], b0[4], b1[4];
    #pragma unroll
    for (int mi=0;mi<4;++mi){
      const unsigned short* p = &Al[(64*wr + 16*mi + l15)*72 + g*8];
      a0[mi] = *reinterpret_cast<const bf16x8*>(p);
      a1[mi] = *reinterpret_cast<const bf16x8*>(p + 32);
    }
    #pragma unroll
    for (int ni=0;ni<4;++ni){
      const unsigned short* p = &Bl[(64*wc + 16*ni + l15)*72 + g*8];
      b0[ni] = *reinterpret_cast<const bf16x8*>(p);
      b1[ni] = *reinterpret_cast<const bf16x8*>(p + 32);
    }
    #pragma unroll
    for (int mi=0;mi<4;++mi)
      #pragma unroll
      for (int ni=0;ni<4;++ni){
        acc[mi][ni] = MFMA16(a0[mi], b0[ni], acc[mi][ni]);
        acc[mi][ni] = MFMA16(a1[mi], b1[ni], acc[mi][ni]);
      }
    __syncthreads();
  }
  #pragma unroll
  for (int mi=0;mi<4;++mi)
    #pragma unroll
    for (int ni=0;ni<4;++ni)
      #pragma unroll
      for (int r=0;r<4;++r){
        int m = m0 + 64*wr + 16*mi + 4*g + r;
        int n = n0 + 64*wc + 16*ni + l15;
        float v = acc[mi][ni][r] + bias[n];
        int b = m >> 11, s = m & 2047;
        int h = n >> 6, d = n & 63;
        Out[(((size_t)(b*NHEAD + h))*SEQ + s)*HDIM + d] = f2bf(v);
      }
}

// ---------------- V transpose: [B,H,S,D] -> [B,H,D,S] ----------------
__global__ void vtrans(const unsigned short* __restrict__ Vb, unsigned short* __restrict__ VTb){
  __shared__ __align__(16) unsigned short Vl[64*72];
  const int tid = threadIdx.x;
  const int blk = blockIdx.x;
  const int st = blk & 31, bh = blk >> 5;
  const int s0 = st*64;
  const unsigned short* src = Vb + (size_t)bh*SEQ*HDIM;
  unsigned short* dst = VTb + (size_t)bh*HDIM*SEQ;
  #pragma unroll
  for (int p=0;p<2;++p){
    int lin = tid + 256*p;
    int row = lin >> 3, ch = lin & 7;
    *reinterpret_cast<bf16x8*>(&Vl[row*72 + ch*8]) =
      *reinterpret_cast<const bf16x8*>(&src[(size_t)(s0+row)*HDIM + ch*8]);
  }
  __syncthreads();
  #pragma unroll
  for (int p=0;p<2;++p){
    int lin = tid + 256*p;
    int drow = lin >> 3, sch = lin & 7;
    bf16x8 v;
    #pragma unroll
    for (int j=0;j<8;++j) v[j] = (short)Vl[(sch*8+j)*72 + drow];
    *reinterpret_cast<bf16x8*>(&dst[(size_t)drow*SEQ + s0 + sch*8]) = v;
  }
}

// ---------------- fused attention: software-pipelined bias production ----------------
// One barrier per k-tile. During iteration kt each wave:
//   consume: S1 = K(kt).Q^T (kb global->reg), merge G1/G2[kt&1] (produced last
//            iter, visible at barrier A), softmax, P->PV (V global->reg).
//   produce: G1/G2 for tile kt+1 from global-loaded ka/E fragments (no LDS
//            staging), stored into parity buffers [(kt+1)&1].
// P repack reuses the just-consumed wave-private G1 slab.
// Index algebra identical to round-5 (verified): G2[96][76] row=qhat+15,
// G1T [80][18-stride] row=t, col=qloc.
__global__ __launch_bounds__(256,3) void attn_kernel(
    const unsigned short* __restrict__ Qb,
    const unsigned short* __restrict__ Kb,
    const unsigned short* __restrict__ VTb,
    const unsigned short* __restrict__ Eb,
    float* __restrict__ out)
{
  __shared__ __align__(16) unsigned short G2k[2][96*76];   // 2 x 14.25 KB
  __shared__ __align__(16) unsigned char  Wslab[4][2][2880]; // per-wave G1T dbuf (P aliases consumed half)

  const int tid = threadIdx.x;
  const int ln = tid & 63, wv = tid >> 6;
  const int l15 = ln & 15, g = ln >> 4;

  const int bid = blockIdx.x;
  const int swz = (bid & 7)*128 + (bid >> 3);   // XCD swizzle (1024 % 8 == 0)
  const int qt = swz & 31, bh = swz >> 5;
  const int q0 = qt*64;

  const unsigned short* Qg = Qb + (size_t)bh*SEQ*HDIM;
  const unsigned short* Kg = Kb + (size_t)bh*SEQ*HDIM;
  const unsigned short* Vg = VTb + (size_t)bh*HDIM*SEQ;

  // Q fragment: lane l15 = q-local row
  bf16x8 qa0, qa1;
  {
    const unsigned short* p = &Qg[(size_t)(q0 + 16*wv + l15)*HDIM + 8*g];
    qa0 = *reinterpret_cast<const bf16x8*>(p);
    qa1 = *reinterpret_cast<const bf16x8*>(p + 32);
  }

  f32x4 oacc[4];
  #pragma unroll
  for (int i=0;i<4;++i) oacc[i] = (f32x4){0.f,0.f,0.f,0.f};
  float mrow = -1e30f, lrow = 0.f;

  const int g1sbase = l15*9 + 2*g;                     // u32 units
  const int g1rbase = (l15 + 12 - 4*g)*18 + l15;       // u16 units
  const int g2sbase = (l15 + 4*g)*76 + (48 - 16*wv + 4*g);
  const int g2rbase = (16*wv + l15 + 15)*76;
  const int kband = 3 - wv;

  // produce G1/G2 for tile starting at k0n (E window base idx_minn) into
  // parity buffers; operands loaded global->reg per-lane (L2-hot).
  auto produce = [&](int k0n, int idx_minn, unsigned* g1dst, unsigned short* g2dst){
    const unsigned short* kp = &Kg[(size_t)(k0n + 16*kband + l15)*HDIM + 8*g];
    bf16x8 ka0 = *reinterpret_cast<const bf16x8*>(kp);
    bf16x8 ka1 = *reinterpret_cast<const bf16x8*>(kp + 32);
    #pragma unroll
    for (int c=0;c<5;++c){
      int er = idx_minn + 16*(wv + c) + l15;
      if (er > 4094) er = 4094;       // t=127 lanes produce pad-row garbage only
      const unsigned short* ep = &Eb[(size_t)er*HDIM + 8*g];
      bf16x8 e0 = *reinterpret_cast<const bf16x8*>(ep);
      bf16x8 e1 = *reinterpret_cast<const bf16x8*>(ep + 32);
      f32x4 a2 = (f32x4){0.f,0.f,0.f,0.f};
      a2 = MFMA16(ka0, e0, a2);
      a2 = MFMA16(ka1, e1, a2);
      f32x4 a1 = (f32x4){0.f,0.f,0.f,0.f};
      a1 = MFMA16(qa0, e0, a1);
      a1 = MFMA16(qa1, e1, a1);
      // G2 raw store: row = 16c+l15+4g+r, col = 16*kband+4g+r  (+77 = +row+col)
      g2dst[g2sbase + c*1216      ] = f2bf(a2[0]);
      g2dst[g2sbase + c*1216 +  77] = f2bf(a2[1]);
      g2dst[g2sbase + c*1216 + 154] = f2bf(a2[2]);
      g2dst[g2sbase + c*1216 + 231] = f2bf(a2[3]);
      // G1 packed store: row t = 16c+l15, cols qloc = 4g..4g+3
      g1dst[g1sbase + c*144    ] = cvtpk(a1[0], a1[1]);
      g1dst[g1sbase + c*144 + 1] = cvtpk(a1[2], a1[3]);
    }
  };

  produce(0, 1984 + q0, (unsigned*)Wslab[wv][0], G2k[0]);

  for (int kt = 0; kt < SEQ/64; ++kt){
    const int k0 = kt*64;
    unsigned short* g1c16 = (unsigned short*)Wslab[wv][kt & 1];
    unsigned*       pc32  = (unsigned*)Wslab[wv][kt & 1];
    const unsigned short* G2c = G2k[kt & 1];

    __syncthreads();   // A: G1/G2(kt) stores (prev iter) visible; prev readers done

    // ---- K fragments for S1 + V fragments for PV: global->reg ----
    bf16x8 kb0[4], kb1[4], vb0[4], vb1[4];
    #pragma unroll
    for (int ct=0;ct<4;++ct){
      const unsigned short* p = &Kg[(size_t)(k0 + 16*ct + l15)*HDIM + 8*g];
      kb0[ct] = *reinterpret_cast<const bf16x8*>(p);
      kb1[ct] = *reinterpret_cast<const bf16x8*>(p + 32);
    }
    #pragma unroll
    for (int ctd=0;ctd<4;++ctd){
      const unsigned short* p = &Vg[(size_t)(16*ctd + l15)*SEQ + k0 + 8*g];
      vb0[ctd] = *reinterpret_cast<const bf16x8*>(p);
      vb1[ctd] = *reinterpret_cast<const bf16x8*>(p + 32);
    }

    // ---- S1 = K.Q^T ----
    __builtin_amdgcn_s_setprio(1);
    f32x4 sacc[4];
    #pragma unroll
    for (int ct=0; ct<4; ++ct){
      f32x4 a = (f32x4){0.f,0.f,0.f,0.f};
      a = MFMA16(kb0[ct], qa0, a);
      a = MFMA16(kb1[ct], qa1, a);
      sacc[ct] = a;
    }
    __builtin_amdgcn_s_setprio(0);

    // ---- produce bias for tile kt+1 (independent of consume chain) ----
    if (kt < SEQ/64 - 1)
      produce(k0 + 64, 1984 + q0 - 64*(kt+1),
              (unsigned*)Wslab[wv][(kt+1) & 1], G2k[(kt+1) & 1]);

    // ---- merge: G1 scalar u16 reads, G2 aligned b64 reads (both ready) ----
    float sc[4][4];
    #pragma unroll
    for (int ct=0; ct<4; ++ct){
      ushort4 u2 = *reinterpret_cast<const ushort4*>(&G2c[g2rbase + 16*ct + 4*g]);
      float t0 = bf2f(g1c16[g1rbase + (51 - 16*ct    )*18]) + bf2f(u2.x);
      float t1 = bf2f(g1c16[g1rbase + (51 - 16*ct - 1)*18]) + bf2f(u2.y);
      float t2 = bf2f(g1c16[g1rbase + (51 - 16*ct - 2)*18]) + bf2f(u2.z);
      float t3 = bf2f(g1c16[g1rbase + (51 - 16*ct - 3)*18]) + bf2f(u2.w);
      sc[ct][0] = fmaf(sacc[ct][0], 0.125f, t0);
      sc[ct][1] = fmaf(sacc[ct][1], 0.125f, t1);
      sc[ct][2] = fmaf(sacc[ct][2], 0.125f, t2);
      sc[ct][3] = fmaf(sacc[ct][3], 0.125f, t3);
    }

    // ---- online softmax (per-lane q-row; reduce across g via shfl 16/32) ----
    float pmax = sc[0][0];
    #pragma unroll
    for (int ct=0;ct<4;++ct)
      #pragma unroll
      for (int r=0;r<4;++r) pmax = fmaxf(pmax, sc[ct][r]);
    pmax = fmaxf(pmax, __shfl_xor(pmax, 16, 64));
    pmax = fmaxf(pmax, __shfl_xor(pmax, 32, 64));
    float mn = fmaxf(pmax, mrow);
    float corr = __expf(mrow - mn);
    const float nm2 = mn * LOG2E;
    float s = 0.f;
    #pragma unroll
    for (int ct=0;ct<4;++ct)
      #pragma unroll
      for (int r=0;r<4;++r){
        float e = exp2f(fmaf(sc[ct][r], LOG2E, -nm2));
        sc[ct][r] = e; s += e;
      }
    s += __shfl_xor(s, 16, 64);
    s += __shfl_xor(s, 32, 64);
    lrow = lrow*corr + s;
    mrow = mn;
    #pragma unroll
    for (int ctd=0;ctd<4;++ctd)
      #pragma unroll
      for (int r=0;r<4;++r) oacc[ctd][r] *= corr;

    // ---- P repack into just-consumed wave-private G1 slab ----
    #pragma unroll
    for (int ct=0;ct<4;++ct){
      pc32[l15*36 + 8*ct + 2*g    ] = cvtpk(sc[ct][0], sc[ct][1]);
      pc32[l15*36 + 8*ct + 2*g + 1] = cvtpk(sc[ct][2], sc[ct][3]);
    }
    asm volatile("" ::: "memory");
    bf16x8 pb0 = *reinterpret_cast<const bf16x8*>(&pc32[l15*36 + 4*g]);
    bf16x8 pb1 = *reinterpret_cast<const bf16x8*>(&pc32[l15*36 + 16 + 4*g]);

    // ---- PV: O^T += V^T . P^T ----
    __builtin_amdgcn_s_setprio(1);
    #pragma unroll
    for (int ctd=0; ctd<4; ++ctd){
      oacc[ctd] = MFMA16(vb0[ctd], pb0, oacc[ctd]);
      oacc[ctd] = MFMA16(vb1[ctd], pb1, oacc[ctd]);
    }
    __builtin_amdgcn_s_setprio(0);
  }

  const int b = bh >> 4, h = bh & 15;
  const float inv = 1.0f / lrow;
  const int q = q0 + 16*wv + l15;
  #pragma unroll
  for (int ctd=0; ctd<4; ++ctd)
    #pragma unroll
    for (int r=0;r<4;++r){
      int d = 16*ctd + 4*g + r;
      out[((size_t)(b*SEQ + q))*HID + h*HDIM + d] = oacc[ctd][r] * inv;
    }
}

// ---------------- launch ----------------
extern "C" void kernel_launch(void* const* d_in, const int* in_sizes, int n_in,
                              void* d_out, int out_size, void* d_ws, size_t ws_size,
                              hipStream_t stream){
  const float* hs = (const float*)d_in[0];
  const float* Wq = (const float*)d_in[1];
  const float* bq = (const float*)d_in[2];
  const float* Wk = (const float*)d_in[3];
  const float* bk = (const float*)d_in[4];
  const float* Wv = (const float*)d_in[5];
  const float* bv = (const float*)d_in[6];
  const float* de = (const float*)d_in[7];
  float* out = (float*)d_out;

  char* ws = (char*)d_ws;
  unsigned short* Xb  = (unsigned short*)(ws);
  unsigned short* Wqb = (unsigned short*)(ws + 8388608);
  unsigned short* Wkb = (unsigned short*)(ws + 8388608 + 2097152);
  unsigned short* Wvb = (unsigned short*)(ws + 8388608 + 2*2097152);
  unsigned short* Eb  = (unsigned short*)(ws + 14680064);
  unsigned short* Qb  = (unsigned short*)(ws + 15204352);
  unsigned short* Kb  = (unsigned short*)(ws + 23592960);
  unsigned short* Vb  = (unsigned short*)(ws + 31981568);
  unsigned short* VTb = (unsigned short*)(ws + 40370176);

  cvt_kernel<<<1024,256,0,stream>>>(hs, Xb, 4194304/4);
  cvt_kernel<<<512,256,0,stream>>>(Wq, Wqb, 1048576/4);
  cvt_kernel<<<512,256,0,stream>>>(Wk, Wkb, 1048576/4);
  cvt_kernel<<<512,256,0,stream>>>(Wv, Wvb, 1048576/4);
  cvt_kernel<<<256,256,0,stream>>>(de, Eb, 262080/4);

  dim3 gg(8,32,3);
  qkv_gemm<<<gg,256,0,stream>>>(Xb, Wqb, Wkb, Wvb, bq, bk, bv, Qb, Kb, Vb);
  vtrans<<<1024,256,0,stream>>>(Vb, VTb);
  attn_kernel<<<1024,256,0,stream>>>(Qb, Kb, VTb, Eb, out);
}

// Round 7
// 223.875 us; speedup vs baseline: 2.5360x; 2.5360x over previous
//
#include <hip/hip_runtime.h>
#include <hip/hip_bf16.h>
#include <stdint.h>

#define SEQ    2048
#define HDIM   64
#define NHEAD  16
#define NBATCH 2
#define HID    1024
#define MAXP   2048
#define LOG2E  1.44269504f

typedef __attribute__((ext_vector_type(8))) short bf16x8;
typedef __attribute__((ext_vector_type(4))) float f32x4;

#define MFMA16(a,b,c) __builtin_amdgcn_mfma_f32_16x16x32_bf16((a),(b),(c),0,0,0)

static __device__ __forceinline__ unsigned short f2bf(float x){
  union { __hip_bfloat16 h; unsigned short u; } c; c.h = __float2bfloat16(x); return c.u;
}
static __device__ __forceinline__ float bf2f(unsigned short u){
  union { __hip_bfloat16 h; unsigned short u; } c; c.u = u; return __bfloat162float(c.h);
}
static __device__ __forceinline__ unsigned cvtpk(float lo, float hi){
  unsigned r;
  asm volatile("v_cvt_pk_bf16_f32 %0, %1, %2" : "=v"(r) : "v"(lo), "v"(hi));
  return r;
}
typedef __attribute__((address_space(1))) const void gv_t;
typedef __attribute__((address_space(3))) void lv_t;
static __device__ __forceinline__ void gload16(const void* g, void* l){
  __builtin_amdgcn_global_load_lds((gv_t*)g, (lv_t*)l, 16, 0, 0);
}

// ---------------- f32 -> bf16 convert ----------------
__global__ void cvt_kernel(const float* __restrict__ src, unsigned short* __restrict__ dst, int n4){
  int i = blockIdx.x*blockDim.x + threadIdx.x;
  int stride = gridDim.x*blockDim.x;
  for (int idx = i; idx < n4; idx += stride){
    float4 v = reinterpret_cast<const float4*>(src)[idx];
    ushort4 o;
    o.x = f2bf(v.x); o.y = f2bf(v.y); o.z = f2bf(v.z); o.w = f2bf(v.w);
    reinterpret_cast<ushort4*>(dst)[idx] = o;
  }
}

// ---------------- QKV projection GEMM ----------------
__global__ __launch_bounds__(256,2) void qkv_gemm(
    const unsigned short* __restrict__ X,
    const unsigned short* __restrict__ Wq_, const unsigned short* __restrict__ Wk_,
    const unsigned short* __restrict__ Wv_,
    const float* __restrict__ bq_, const float* __restrict__ bk_, const float* __restrict__ bv_,
    unsigned short* __restrict__ Qb, unsigned short* __restrict__ Kb, unsigned short* __restrict__ Vb)
{
  __shared__ __align__(16) unsigned short Al[128*72];
  __shared__ __align__(16) unsigned short Bl[128*72];
  const int tid = threadIdx.x;
  const int ln = tid & 63, wv = tid >> 6;
  const int l15 = ln & 15, g = ln >> 4;
  const int wr = wv >> 1, wc = wv & 1;

  const int bn = blockIdx.x, bm = blockIdx.y, mat = blockIdx.z;
  const unsigned short* W = (mat==0) ? Wq_ : ((mat==1) ? Wk_ : Wv_);
  const float* bias = (mat==0) ? bq_ : ((mat==1) ? bk_ : bv_);
  unsigned short* Out = (mat==0) ? Qb : ((mat==1) ? Kb : Vb);

  const int m0 = bm*128, n0 = bn*128;

  f32x4 acc[4][4];
  #pragma unroll
  for (int i=0;i<4;++i)
    #pragma unroll
    for (int j=0;j<4;++j) acc[i][j] = (f32x4){0.f,0.f,0.f,0.f};

  for (int kk = 0; kk < HID; kk += 64){
    #pragma unroll
    for (int p=0;p<4;++p){
      int lin = tid + 256*p;
      int row = lin >> 3, ch = lin & 7;
      *reinterpret_cast<bf16x8*>(&Al[row*72 + ch*8]) =
        *reinterpret_cast<const bf16x8*>(&X[(size_t)(m0+row)*HID + kk + ch*8]);
      *reinterpret_cast<bf16x8*>(&Bl[row*72 + ch*8]) =
        *reinterpret_cast<const bf16x8*>(&W[(size_t)(n0+row)*HID + kk + ch*8]);
    }
    __syncthreads();
    bf16x8 a0[4], a1[4], b0[4], b1[4];
    #pragma unroll
    for (int mi=0;mi<4;++mi){
      const unsigned short* p = &Al[(64*wr + 16*mi + l15)*72 + g*8];
      a0[mi] = *reinterpret_cast<const bf16x8*>(p);
      a1[mi] = *reinterpret_cast<const bf16x8*>(p + 32);
    }
    #pragma unroll
    for (int ni=0;ni<4;++ni){
      const unsigned short* p = &Bl[(64*wc + 16*ni + l15)*72 + g*8];
      b0[ni] = *reinterpret_cast<const bf16x8*>(p);
      b1[ni] = *reinterpret_cast<const bf16x8*>(p + 32);
    }
    #pragma unroll
    for (int mi=0;mi<4;++mi)
      #pragma unroll
      for (int ni=0;ni<4;++ni){
        acc[mi][ni] = MFMA16(a0[mi], b0[ni], acc[mi][ni]);
        acc[mi][ni] = MFMA16(a1[mi], b1[ni], acc[mi][ni]);
      }
    __syncthreads();
  }
  #pragma unroll
  for (int mi=0;mi<4;++mi)
    #pragma unroll
    for (int ni=0;ni<4;++ni)
      #pragma unroll
      for (int r=0;r<4;++r){
        int m = m0 + 64*wr + 16*mi + 4*g + r;
        int n = n0 + 64*wc + 16*ni + l15;
        float v = acc[mi][ni][r] + bias[n];
        int b = m >> 11, s = m & 2047;
        int h = n >> 6, d = n & 63;
        Out[(((size_t)(b*NHEAD + h))*SEQ + s)*HDIM + d] = f2bf(v);
      }
}

// ---------------- V transpose: [B,H,S,D] -> [B,H,D,S] ----------------
__global__ void vtrans(const unsigned short* __restrict__ Vb, unsigned short* __restrict__ VTb){
  __shared__ __align__(16) unsigned short Vl[64*72];
  const int tid = threadIdx.x;
  const int blk = blockIdx.x;
  const int st = blk & 31, bh = blk >> 5;
  const int s0 = st*64;
  const unsigned short* src = Vb + (size_t)bh*SEQ*HDIM;
  unsigned short* dst = VTb + (size_t)bh*HDIM*SEQ;
  #pragma unroll
  for (int p=0;p<2;++p){
    int lin = tid + 256*p;
    int row = lin >> 3, ch = lin & 7;
    *reinterpret_cast<bf16x8*>(&Vl[row*72 + ch*8]) =
      *reinterpret_cast<const bf16x8*>(&src[(size_t)(s0+row)*HDIM + ch*8]);
  }
  __syncthreads();
  #pragma unroll
  for (int p=0;p<2;++p){
    int lin = tid + 256*p;
    int drow = lin >> 3, sch = lin & 7;
    bf16x8 v;
    #pragma unroll
    for (int j=0;j<8;++j) v[j] = (short)Vl[(sch*8+j)*72 + drow];
    *reinterpret_cast<bf16x8*>(&dst[(size_t)drow*SEQ + s0 + sch*8]) = v;
  }
}

// ---------------- fused attention (round-5 structure, occupancy-tuned) ----------------
// 512 blocks x 2 sequential q-tiles (one clean residency generation, 2 blocks/CU).
// V loads moved to post-merge (shortens vb liveness -> lower VGPR).
// G2 stride 76 -> 72 (13.5 KB). Everything else identical to the verified round-5.
__global__ __launch_bounds__(256,3) void attn_kernel(
    const unsigned short* __restrict__ Qb,
    const unsigned short* __restrict__ Kb,
    const unsigned short* __restrict__ VTb,
    const unsigned short* __restrict__ Eb,
    float* __restrict__ out)
{
  __shared__ __align__(16) unsigned short E_l[128*64];   // 16 KB swizzled
  __shared__ __align__(16) unsigned short K_l[64*64];    // 8 KB swizzled
  __shared__ __align__(16) unsigned short G2k[96*72];    // 13.5 KB
  __shared__ __align__(16) unsigned char  Wslab[4][2880]; // G1T (2880B) U P (2304B)

  const int tid = threadIdx.x;
  const int ln = tid & 63, wv = tid >> 6;
  const int l15 = ln & 15, g = ln >> 4;
  const int rsub = ln >> 3, csub = ln & 7;
  const int swch = csub ^ rsub;               // swizzled source chunk (staging)
  const int x7 = l15 & 7;
  const int c0 = (g ^ x7) * 8;                // swizzled read col, d-half 0
  const int c1 = c0 ^ 32;

  const int bid = blockIdx.x;
  const int swz = (bid & 7)*64 + (bid >> 3);  // XCD swizzle (512 % 8 == 0)
  const int qtp = swz & 15, bh = swz >> 4;

  const unsigned short* Qg = Qb + (size_t)bh*SEQ*HDIM;
  const unsigned short* Kg = Kb + (size_t)bh*SEQ*HDIM;
  const unsigned short* Vg = VTb + (size_t)bh*HDIM*SEQ;

  unsigned short* g1w16 = (unsigned short*)Wslab[wv];
  unsigned*       g1w32 = (unsigned*)Wslab[wv];
  unsigned*       pww   = (unsigned*)Wslab[wv];
  const int g1sbase = l15*9 + 2*g;                     // u32 units
  const int g1rbase = (l15 + 12 - 4*g)*18 + l15;       // u16 units
  const int g2sbase = (l15 + 4*g)*72 + (48 - 16*wv + 4*g);
  const int g2rbase = (16*wv + l15 + 15)*72;
  const int kband = 3 - wv;

  auto stageK = [&](int k0n){
    #pragma unroll
    for (int p=0;p<2;++p){
      int rb = 32*p + 8*wv;
      gload16(&Kg[(size_t)(k0n + rb + rsub)*HDIM + swch*8], (char*)K_l + rb*128);
    }
  };
  auto stageE = [&](int row0){
    #pragma unroll
    for (int p=0;p<4;++p){
      int rb = 32*p + 8*wv;
      int er = row0 + rb + rsub;
      if (er > 4094) er = 4094;               // window row 127 unused; keep in-bounds
      gload16(&Eb[(size_t)er*HDIM + swch*8], (char*)E_l + rb*128);
    }
  };

  for (int qq = 0; qq < 2; ++qq){
    const int qt = qtp*2 + qq;
    const int q0 = qt*64;

    // Q fragment: lane l15 = q-local row
    bf16x8 qa0, qa1;
    {
      const unsigned short* p = &Qg[(size_t)(q0 + 16*wv + l15)*HDIM + 8*g];
      qa0 = *reinterpret_cast<const bf16x8*>(p);
      qa1 = *reinterpret_cast<const bf16x8*>(p + 32);
    }

    f32x4 oacc[4];
    #pragma unroll
    for (int i=0;i<4;++i) oacc[i] = (f32x4){0.f,0.f,0.f,0.f};
    float mrow = -1e30f, lrow = 0.f;

    const int idx0 = 1984 + q0;               // E window base at kt=0
    stageK(0);
    stageE(idx0);

    for (int kt = 0; kt < SEQ/64; ++kt){
      const int k0 = kt*64;
      __syncthreads();   // A: staging complete; prev-iter G2k reads complete

      __builtin_amdgcn_s_setprio(1);
      bf16x8 ka0, ka1;
      {
        int R = 16*kband + l15;
        ka0 = *reinterpret_cast<const bf16x8*>(&K_l[R*64 + c0]);
        ka1 = *reinterpret_cast<const bf16x8*>(&K_l[R*64 + c1]);
      }
      // ---- shared E-tile loop: G2 + G1 production, unconditional stores ----
      #pragma unroll
      for (int c=0;c<5;++c){
        int tt = wv + c;
        bf16x8 eb_0 = *reinterpret_cast<const bf16x8*>(&E_l[(16*tt + l15)*64 + c0]);
        bf16x8 eb_1 = *reinterpret_cast<const bf16x8*>(&E_l[(16*tt + l15)*64 + c1]);
        f32x4 a2 = (f32x4){0.f,0.f,0.f,0.f};
        a2 = MFMA16(ka0, eb_0, a2);
        a2 = MFMA16(ka1, eb_1, a2);
        f32x4 a1v = (f32x4){0.f,0.f,0.f,0.f};
        a1v = MFMA16(qa0, eb_0, a1v);
        a1v = MFMA16(qa1, eb_1, a1v);
        // G2 raw: row = 16c+l15+4g+r, col = khat = 16*kband+4g+r  (+73 per r)
        G2k[g2sbase + c*1152      ] = f2bf(a2[0]);
        G2k[g2sbase + c*1152 +  73] = f2bf(a2[1]);
        G2k[g2sbase + c*1152 + 146] = f2bf(a2[2]);
        G2k[g2sbase + c*1152 + 219] = f2bf(a2[3]);
        // G1 packed: row t = 16c+l15, cols qloc = 4g..4g+3
        g1w32[g1sbase + c*144    ] = cvtpk(a1v[0], a1v[1]);
        g1w32[g1sbase + c*144 + 1] = cvtpk(a1v[2], a1v[3]);
      }
      // ---- S1 = K.Q^T ----
      f32x4 sacc[4];
      #pragma unroll
      for (int ct=0; ct<4; ++ct){
        int R = 16*ct + l15;
        bf16x8 kb0 = *reinterpret_cast<const bf16x8*>(&K_l[R*64 + c0]);
        bf16x8 kb1 = *reinterpret_cast<const bf16x8*>(&K_l[R*64 + c1]);
        f32x4 a = (f32x4){0.f,0.f,0.f,0.f};
        a = MFMA16(kb0, qa0, a);
        a = MFMA16(kb1, qa1, a);
        sacc[ct] = a;
      }
      __builtin_amdgcn_s_setprio(0);
      __syncthreads();   // B: G2k visible; all E/K reads complete

      if (kt < SEQ/64 - 1){
        stageK(k0 + 64);
        stageE(idx0 - 64*(kt+1));
      }

      // ---- merge: G1 scalar u16 reads, G2 aligned b64 reads ----
      float sc[4][4];
      #pragma unroll
      for (int ct=0; ct<4; ++ct){
        ushort4 u2 = *reinterpret_cast<const ushort4*>(&G2k[g2rbase + 16*ct + 4*g]);
        float t0 = bf2f(g1w16[g1rbase + (51 - 16*ct    )*18]) + bf2f(u2.x);
        float t1 = bf2f(g1w16[g1rbase + (51 - 16*ct - 1)*18]) + bf2f(u2.y);
        float t2 = bf2f(g1w16[g1rbase + (51 - 16*ct - 2)*18]) + bf2f(u2.z);
        float t3 = bf2f(g1w16[g1rbase + (51 - 16*ct - 3)*18]) + bf2f(u2.w);
        sc[ct][0] = fmaf(sacc[ct][0], 0.125f, t0);
        sc[ct][1] = fmaf(sacc[ct][1], 0.125f, t1);
        sc[ct][2] = fmaf(sacc[ct][2], 0.125f, t2);
        sc[ct][3] = fmaf(sacc[ct][3], 0.125f, t3);
      }

      // ---- V fragments: global->reg, issued here so softmax+P covers latency ----
      bf16x8 vb0[4], vb1[4];
      #pragma unroll
      for (int ctd=0;ctd<4;++ctd){
        const unsigned short* p = &Vg[(size_t)(16*ctd + l15)*SEQ + k0 + 8*g];
        vb0[ctd] = *reinterpret_cast<const bf16x8*>(p);
        vb1[ctd] = *reinterpret_cast<const bf16x8*>(p + 32);
      }

      // ---- online softmax (per-lane q-row; reduce across g via shfl 16/32) ----
      float pmax = sc[0][0];
      #pragma unroll
      for (int ct=0;ct<4;++ct)
        #pragma unroll
        for (int r=0;r<4;++r) pmax = fmaxf(pmax, sc[ct][r]);
      pmax = fmaxf(pmax, __shfl_xor(pmax, 16, 64));
      pmax = fmaxf(pmax, __shfl_xor(pmax, 32, 64));
      float mn = fmaxf(pmax, mrow);
      float corr = __expf(mrow - mn);
      const float nm2 = mn * LOG2E;
      float s = 0.f;
      #pragma unroll
      for (int ct=0;ct<4;++ct)
        #pragma unroll
        for (int r=0;r<4;++r){
          float e = exp2f(fmaf(sc[ct][r], LOG2E, -nm2));
          sc[ct][r] = e; s += e;
        }
      s += __shfl_xor(s, 16, 64);
      s += __shfl_xor(s, 32, 64);
      lrow = lrow*corr + s;
      mrow = mn;
      #pragma unroll
      for (int ctd=0;ctd<4;++ctd)
        #pragma unroll
        for (int r=0;r<4;++r) oacc[ctd][r] *= corr;

      // ---- P repack (aliases G1 slab; data-dependence orders reads/writes) ----
      #pragma unroll
      for (int ct=0;ct<4;++ct){
        pww[l15*36 + 8*ct + 2*g    ] = cvtpk(sc[ct][0], sc[ct][1]);
        pww[l15*36 + 8*ct + 2*g + 1] = cvtpk(sc[ct][2], sc[ct][3]);
      }
      asm volatile("" ::: "memory");
      bf16x8 pb0 = *reinterpret_cast<const bf16x8*>(&pww[l15*36 + 4*g]);
      bf16x8 pb1 = *reinterpret_cast<const bf16x8*>(&pww[l15*36 + 16 + 4*g]);

      // ---- PV: O^T += V^T . P^T ----
      __builtin_amdgcn_s_setprio(1);
      #pragma unroll
      for (int ctd=0; ctd<4; ++ctd){
        oacc[ctd] = MFMA16(vb0[ctd], pb0, oacc[ctd]);
        oacc[ctd] = MFMA16(vb1[ctd], pb1, oacc[ctd]);
      }
      __builtin_amdgcn_s_setprio(0);
    }

    const int b = bh >> 4, h = bh & 15;
    const float inv = 1.0f / lrow;
    const int q = q0 + 16*wv + l15;
    #pragma unroll
    for (int ctd=0; ctd<4; ++ctd)
      #pragma unroll
      for (int r=0;r<4;++r){
        int d = 16*ctd + 4*g + r;
        out[((size_t)(b*SEQ + q))*HID + h*HDIM + d] = oacc[ctd][r] * inv;
      }
  }
}

// ---------------- launch ----------------
extern "C" void kernel_launch(void* const* d_in, const int* in_sizes, int n_in,
                              void* d_out, int out_size, void* d_ws, size_t ws_size,
                              hipStream_t stream){
  const float* hs = (const float*)d_in[0];
  const float* Wq = (const float*)d_in[1];
  const float* bq = (const float*)d_in[2];
  const float* Wk = (const float*)d_in[3];
  const float* bk = (const float*)d_in[4];
  const float* Wv = (const float*)d_in[5];
  const float* bv = (const float*)d_in[6];
  const float* de = (const float*)d_in[7];
  float* out = (float*)d_out;

  char* ws = (char*)d_ws;
  unsigned short* Xb  = (unsigned short*)(ws);
  unsigned short* Wqb = (unsigned short*)(ws + 8388608);
  unsigned short* Wkb = (unsigned short*)(ws + 8388608 + 2097152);
  unsigned short* Wvb = (unsigned short*)(ws + 8388608 + 2*2097152);
  unsigned short* Eb  = (unsigned short*)(ws + 14680064);
  unsigned short* Qb  = (unsigned short*)(ws + 15204352);
  unsigned short* Kb  = (unsigned short*)(ws + 23592960);
  unsigned short* Vb  = (unsigned short*)(ws + 31981568);
  unsigned short* VTb = (unsigned short*)(ws + 40370176);

  cvt_kernel<<<1024,256,0,stream>>>(hs, Xb, 4194304/4);
  cvt_kernel<<<512,256,0,stream>>>(Wq, Wqb, 1048576/4);
  cvt_kernel<<<512,256,0,stream>>>(Wk, Wkb, 1048576/4);
  cvt_kernel<<<512,256,0,stream>>>(Wv, Wvb, 1048576/4);
  cvt_kernel<<<256,256,0,stream>>>(de, Eb, 262080/4);

  dim3 gg(8,32,3);
  qkv_gemm<<<gg,256,0,stream>>>(Xb, Wqb, Wkb, Wvb, bq, bk, bv, Qb, Kb, Vb);
  vtrans<<<1024,256,0,stream>>>(Vb, VTb);
  attn_kernel<<<512,256,0,stream>>>(Qb, Kb, VTb, Eb, out);
}